// Round 1
// baseline (87.044 us; speedup 1.0000x reference)
//
#include <hip/hip_runtime.h>
#include <stdint.h>

// Problem constants (from reference)
#define IN_SCALE 23
#define DDIM 529            // 23*23
#define BATCH 2
#define BITS 32
#define HDC 512
#define NNZ_REGION (DDIM * HDC)          // 270848 — indices fall only in here
#define SMALL (5 * BATCH * DDIM)         // 5290 small output floats
#define BIN_PER_OUT (BATCH * DDIM * BITS * HDC)  // 17334272
#define BIN_PER_B   (DDIM * BITS * HDC)          // 8667136

// Scatter: mask[idx] = 1 (duplicates benign, same value)
__global__ void scatter_mask(const int* __restrict__ idx, int n,
                             uint8_t* __restrict__ mask) {
    int i = blockIdx.x * blockDim.x + threadIdx.x;
    if (i < n) {
        int p = idx[i];
        if (p >= 0 && p < NNZ_REGION) mask[p] = 1;
    }
}

// Small outputs r,g,b,a,s (5290 floats) + stash their int32 bit-words for the
// bins kernel.
__global__ void small_outputs(const float* __restrict__ data,
                              const float* __restrict__ structure,
                              const float* __restrict__ params,
                              float* __restrict__ out,
                              int* __restrict__ xw) {
    int i = blockIdx.x * blockDim.x + threadIdx.x;
    if (i >= SMALL) return;
    int c   = i / (BATCH * DDIM);
    int rem = i % (BATCH * DDIM);
    int bb  = rem / DDIM;
    int d   = rem % DDIM;
    float v;
    if (c < 4) {
        // data_input flat: [B][4*23][23] = [B][2116]; channel c is rows c*23..c*23+22
        v = data[bb * (4 * DDIM) + c * DDIM + d];
    } else {
        v = structure[bb * DDIM + d] * params[d];
    }
    out[i] = v;
    xw[i] = __float_as_int(v);
}

// One block per (c, bb, d): writes 32*512 = 16384 floats (0.0/1.0),
// value = bit_of(word, bit) ^ mask[d*16384 + bit*512 + h]  (batch 0 only).
__global__ __launch_bounds__(256) void bins_kernel(const int* __restrict__ xw,
                                                   const uint8_t* __restrict__ mask,
                                                   float* __restrict__ out) {
    int blk = blockIdx.x;                 // 0..5289, same flat index as xw
    int c   = blk / (BATCH * DDIM);
    int rem = blk % (BATCH * DDIM);
    int bb  = rem / DDIM;
    int d   = rem % DDIM;
    int x   = xw[blk];

    long long base_elem = (long long)SMALL + (long long)c * BIN_PER_OUT
                        + (long long)bb * BIN_PER_B
                        + (long long)d * (BITS * HDC);
    // base_elem is even; bins region is 8B-aligned -> float2 stores
    float2* o = (float2*)out + (base_elem >> 1);

    int t = threadIdx.x;                  // 0..255 -> h2 index (2 floats each)
    const int dbase = d * (BITS * HDC);
    #pragma unroll
    for (int j = 0; j < BITS; ++j) {      // j == bit
        int bv = (x >> j) & 1;
        float f = (float)bv;
        float2 v = make_float2(f, f);
        int p = dbase + j * HDC + t * 2;  // flat proj index (batch-0 frame)
        if (bb == 0 && p < NNZ_REGION) {  // wave-uniform (bounds multiple of 512)
            v.x = (float)(bv ^ (int)mask[p]);
            v.y = (float)(bv ^ (int)mask[p + 1]);
        }
        o[j * 256 + t] = v;
    }
}

extern "C" void kernel_launch(void* const* d_in, const int* in_sizes, int n_in,
                              void* d_out, int out_size, void* d_ws, size_t ws_size,
                              hipStream_t stream) {
    const float* data      = (const float*)d_in[0];
    const float* structure = (const float*)d_in[1];
    const float* params    = (const float*)d_in[2];
    const int*   nzi       = (const int*)d_in[3];
    int nnz = in_sizes[3];

    float*   out  = (float*)d_out;
    uint8_t* mask = (uint8_t*)d_ws;                      // 270848 bytes
    int*     xw   = (int*)((char*)d_ws + NNZ_REGION);    // 5290 int32 (offset is 4B-aligned)

    // Rebuild mask every call (ws is poisoned once; determinism required).
    hipMemsetAsync(mask, 0, NNZ_REGION, stream);
    scatter_mask<<<(nnz + 255) / 256, 256, 0, stream>>>(nzi, nnz, mask);
    small_outputs<<<(SMALL + 255) / 256, 256, 0, stream>>>(data, structure, params, out, xw);
    bins_kernel<<<SMALL, 256, 0, stream>>>(xw, mask, out);
}

// Round 2
// 86.103 us; speedup vs baseline: 1.0109x; 1.0109x over previous
//
#include <hip/hip_runtime.h>
#include <stdint.h>

// Problem constants (from reference)
#define IN_SCALE 23
#define DDIM 529                         // 23*23
#define BATCH 2
#define BITS 32
#define HDC 512
#define ROW (BITS * HDC)                 // 16384 floats per (c,bb,d)
#define NNZ_REGION (DDIM * HDC)          // 270848 — indices only land here (batch 0, d<=16)
#define SMALL (5 * BATCH * DDIM)         // 5290 small output floats (== 2 mod 4)
#define BIN_PER_OUT (BATCH * DDIM * ROW) // 17334272
#define BIN_PER_B   (DDIM * ROW)         // 8667136

// Scatter: mask[idx] = 1 (duplicates benign, same value)
__global__ void scatter_mask(const int* __restrict__ idx, int n,
                             uint8_t* __restrict__ mask) {
    int i = blockIdx.x * blockDim.x + threadIdx.x;
    if (i < n) {
        int p = idx[i];
        if ((unsigned)p < NNZ_REGION) mask[p] = 1;
    }
}

// One block per (c, bb, d). Computes its own scalar value v from the tiny
// inputs (fused small_outputs), writes out[blk] = v, then streams the 16384
// bin floats: val = bit_j(v) ^ mask[d*16384 + e]   (only bb==0, p<NNZ_REGION).
// Bins region starts at float offset 5290 (== 2 mod 4): 2-float head, 4095
// aligned float4, 2-float tail.
__global__ __launch_bounds__(256) void bins_kernel(const float* __restrict__ data,
                                                   const float* __restrict__ structure,
                                                   const float* __restrict__ params,
                                                   const uint8_t* __restrict__ mask,
                                                   float* __restrict__ out) {
    int blk = blockIdx.x;                 // 0..5289 == small-output flat index
    int c   = blk / (BATCH * DDIM);
    int rem = blk % (BATCH * DDIM);
    int bb  = rem / DDIM;
    int d   = rem % DDIM;

    float v;
    if (c < 4) {
        // data_input flat [B][4*23][23]; channel c = rows c*23..c*23+22
        v = data[bb * (4 * DDIM) + c * DDIM + d];
    } else {
        v = structure[bb * DDIM + d] * params[d];
    }
    const int x = __float_as_int(v);

    const bool useMask = (bb == 0);       // mask only ever hits batch 0
    const int  dbase   = d * ROW;         // flat proj byte index base
    long long base = (long long)SMALL + (long long)c * BIN_PER_OUT
                   + (long long)bb * BIN_PER_B + (long long)d * ROW;
    float* o = out + base;                // base == 2 mod 4

    int t = threadIdx.x;
    if (t == 0) {
        out[blk] = v;                     // fused small output
        // head: e = 0,1 (bit j=0)
        int b0 = x & 1, v0 = b0, v1 = b0;
        if (useMask && dbase < NNZ_REGION) { v0 ^= mask[dbase]; v1 ^= mask[dbase + 1]; }
        *(float2*)o = make_float2((float)v0, (float)v1);
    } else if (t == 1) {
        // tail: e = 16382,16383 (bit j=31)
        int b31 = (x >> 31) & 1, v0 = b31, v1 = b31;
        int p = dbase + ROW - 2;
        if (useMask && p < NNZ_REGION) { v0 ^= mask[p]; v1 ^= mask[p + 1]; }
        *(float2*)(o + ROW - 2) = make_float2((float)v0, (float)v1);
    }

    // middle: 4095 float4 at o+2 (16B aligned)
    float4* om = (float4*)(o + 2);
    #pragma unroll
    for (int k = 0; k < 16; ++k) {
        int q = t + k * 256;
        if (q < 4095) {
            int e0 = 2 + q * 4;
            float4 w;
            float* wp = (float*)&w;
            #pragma unroll
            for (int u = 0; u < 4; ++u) {
                int e  = e0 + u;
                int bv = (x >> (e >> 9)) & 1;   // bit j = e/512
                int p  = dbase + e;
                if (useMask && p < NNZ_REGION) bv ^= mask[p];
                wp[u] = (float)bv;
            }
            om[q] = w;
        }
    }
}

extern "C" void kernel_launch(void* const* d_in, const int* in_sizes, int n_in,
                              void* d_out, int out_size, void* d_ws, size_t ws_size,
                              hipStream_t stream) {
    const float* data      = (const float*)d_in[0];
    const float* structure = (const float*)d_in[1];
    const float* params    = (const float*)d_in[2];
    const int*   nzi       = (const int*)d_in[3];
    int nnz = in_sizes[3];

    float*   out  = (float*)d_out;
    uint8_t* mask = (uint8_t*)d_ws;       // 270848 bytes of scratch

    // Rebuild mask every call (ws poisoned once; determinism required).
    hipMemsetAsync(mask, 0, NNZ_REGION, stream);
    scatter_mask<<<(nnz + 255) / 256, 256, 0, stream>>>(nzi, nnz, mask);
    bins_kernel<<<SMALL, 256, 0, stream>>>(data, structure, params, mask, out);
}